// Round 1
// baseline (457.270 us; speedup 1.0000x reference)
//
#include <hip/hip_runtime.h>
#include <stdint.h>

typedef unsigned short u16;
typedef unsigned int u32;
typedef short bf16x8 __attribute__((ext_vector_type(8)));
typedef float f32x4 __attribute__((ext_vector_type(4)));

#define DEVI static __device__ __forceinline__

// ---- fixed problem shapes ----
#define B_ 2
#define T_ 2048
#define C_ 1024
#define H_ 16
#define D_ 64
#define P_ 2048
#define M_ (B_ * T_)   // 4096
#define N1_ (3 * C_)   // 3072
#define LOG2E 1.44269504088896340736f

DEVI u16 f2bf(float f) {
  union { float f; u32 u; } v; v.f = f;
  u32 r = v.u + 0x7fffu + ((v.u >> 16) & 1u);  // RNE
  return (u16)(r >> 16);
}

DEVI void gld_lds16(const void* g, void* l) {
  __builtin_amdgcn_global_load_lds((__attribute__((address_space(1))) void*)g,
                                   (__attribute__((address_space(3))) void*)l,
                                   16, 0, 0);
}

// ---------- cast f32 -> bf16 (vectorized) ----------
__global__ void k_cast(const float* __restrict__ src, u16* __restrict__ dst, int n) {
  int i = (blockIdx.x * 256 + threadIdx.x) * 4;
  if (i >= n) return;
  float4 v = *(const float4*)(src + i);
  ushort4 o;
  o.x = f2bf(v.x); o.y = f2bf(v.y); o.z = f2bf(v.z); o.w = f2bf(v.w);
  *(ushort4*)(dst + i) = o;
}

// ---------- transpose+cast: src[R][C] f32 -> dst[C][R] bf16 ----------
__global__ void k_tcast(const float* __restrict__ src, u16* __restrict__ dst,
                        int R, int C) {
  __shared__ float t[32][33];
  int c0 = blockIdx.x * 32, r0 = blockIdx.y * 32;
  int tx = threadIdx.x, ty = threadIdx.y;
  for (int i = ty; i < 32; i += 8)
    t[i][tx] = src[(size_t)(r0 + i) * C + c0 + tx];
  __syncthreads();
  for (int i = ty; i < 32; i += 8)
    dst[(size_t)(c0 + i) * R + r0 + tx] = f2bf(t[tx][i]);
}

// ---------- GEMM: A[M][K] bf16 (row-major), Bt[N][K] bf16 -> out ----------
// MODE 0: qkv epilogue (scatter to q/k/v in (B,H,T,D), q scaled by 1/8*log2e)
// MODE 1: plain fp32 row-major output [M][N]
template <int MODE>
__launch_bounds__(256)
__global__ void k_gemm(const u16* __restrict__ A, const u16* __restrict__ Bt,
                       void* __restrict__ out0, void* __restrict__ out1,
                       void* __restrict__ out2, int N, int K) {
  __shared__ __align__(16) u16 lA[2][128 * 32];
  __shared__ __align__(16) u16 lB[2][128 * 32];
  const int tid = threadIdx.x, lane = tid & 63, wid = tid >> 6;
  const int wr = wid >> 1, wc = wid & 1;
  const int c = lane & 15, g = lane >> 4;
  const int nt = blockIdx.x, mt = blockIdx.y;
  const int nk = K >> 5;

  f32x4 acc[4][4] = {};

  // stage one 128x32 tile of A and of Bt into buf (linear LDS dest,
  // pre-swizzled global source: byte-in-row ^= (row&3)<<4, rows are 64B)
  auto stage = [&](int buf, int kt) {
    for (int r = 0; r < 2; ++r) {
      int ci = wid * 2 + r;
      int row = ci * 16 + (lane >> 2);
      int gb = ((lane & 3) * 16) ^ ((row & 3) << 4);
      gld_lds16((const char*)A + ((size_t)(mt * 128 + row) * K + kt * 32) * 2 + gb,
                &lA[buf][ci * 512]);
      gld_lds16((const char*)Bt + ((size_t)(nt * 128 + row) * K + kt * 32) * 2 + gb,
                &lB[buf][ci * 512]);
    }
  };

  stage(0, 0);
  int cur = 0;
  for (int kt = 0; kt < nk; ++kt) {
    __syncthreads();            // drains vmcnt: buf[cur] ready
    if (kt + 1 < nk) stage(cur ^ 1, kt + 1);
    const char* pa = (const char*)&lA[cur][0];
    const char* pb = (const char*)&lB[cur][0];
    bf16x8 af[4], bfr[4];
#pragma unroll
    for (int i = 0; i < 4; ++i) {
      int ar = wr * 64 + i * 16 + c;
      af[i] = *(const bf16x8*)(pa + ar * 64 + ((g * 16) ^ ((ar & 3) << 4)));
      int br = wc * 64 + i * 16 + c;
      bfr[i] = *(const bf16x8*)(pb + br * 64 + ((g * 16) ^ ((br & 3) << 4)));
    }
#pragma unroll
    for (int i = 0; i < 4; ++i)
#pragma unroll
      for (int j = 0; j < 4; ++j)
        acc[i][j] = __builtin_amdgcn_mfma_f32_16x16x32_bf16(af[i], bfr[j], acc[i][j], 0, 0, 0);
    cur ^= 1;
  }

  if (MODE == 0) {
    const float qs = 0.125f * LOG2E;  // 1/sqrt(D) * log2(e) folded into q
#pragma unroll
    for (int i = 0; i < 4; ++i) {
      int rbase = mt * 128 + wr * 64 + i * 16 + g * 4;
#pragma unroll
      for (int j = 0; j < 4; ++j) {
        int col = nt * 128 + wc * 64 + j * 16 + c;
        int which = col >> 10, cc = col & 1023;
        int h = cc >> 6, d = cc & 63;
        u16* dst = which == 0 ? (u16*)out0 : (which == 1 ? (u16*)out1 : (u16*)out2);
        float sc = which == 0 ? qs : 1.0f;
#pragma unroll
        for (int r = 0; r < 4; ++r) {
          int m = rbase + r;
          int b = m >> 11, t = m & 2047;
          dst[((size_t)(b * H_ + h) * T_ + t) * D_ + d] = f2bf(acc[i][j][r] * sc);
        }
      }
    }
  } else {
    float* O = (float*)out0;
#pragma unroll
    for (int i = 0; i < 4; ++i) {
      int rbase = mt * 128 + wr * 64 + i * 16 + g * 4;
#pragma unroll
      for (int j = 0; j < 4; ++j) {
        int col = nt * 128 + wc * 64 + j * 16 + c;
#pragma unroll
        for (int r = 0; r < 4; ++r)
          O[(size_t)(rbase + r) * N + col] = acc[i][j][r];
      }
    }
  }
}

// ---------- flash attention over [prefix P=2048][causal self T] ----------
// grid: (T/64 qtiles, B*H). 256 thr = 4 waves, 16 q-rows per wave.
// q pre-scaled by 1/8*log2e -> exp2-based online softmax.
__launch_bounds__(256)
__global__ void k_attn(const u16* __restrict__ qt, const u16* __restrict__ kts,
                       const u16* __restrict__ vts, const u16* __restrict__ ckb,
                       const u16* __restrict__ cvb, u16* __restrict__ y) {
  __shared__ __align__(16) u16 lK[2][64 * 64];   // [key][d], XOR-swizzled
  __shared__ __align__(16) u16 lV[2][64 * 64];   // [d][key] transposed, swizzled
  __shared__ __align__(16) u16 lP[4][16 * 64];   // per-wave P, swizzled
  const int tid = threadIdx.x, lane = tid & 63, wid = tid >> 6;
  const int c = lane & 15, g = lane >> 4;
  const int qtile = blockIdx.x, bh = blockIdx.y;
  const int qbase = qtile * 64;
  const size_t hoff = (size_t)bh * (P_ * D_);

  // Q fragments (A-operand): row = c, k(d) = 8g+j (and +32)
  const u16* qp = qt + hoff + (size_t)(qbase + wid * 16 + c) * D_;
  const bf16x8 q0 = *(const bf16x8*)(qp + g * 8);
  const bf16x8 q1 = *(const bf16x8*)(qp + 32 + g * 8);

  float m_[4], l_[4];
  f32x4 acc[4] = {};
#pragma unroll
  for (int r = 0; r < 4; ++r) { m_[r] = -3.0e38f; l_[r] = 0.0f; }

  const int nPre = P_ / 64;            // 32 prefix tiles
  const int ntl = nPre + qtile + 1;    // + self tiles, last one masked

  uint4 vr0, vr1;

  auto kbase = [&](int t) -> const u16* {
    return (t < nPre) ? ckb + hoff + (size_t)t * 64 * D_
                      : kts + hoff + (size_t)(t - nPre) * 64 * D_;
  };
  auto vbase = [&](int t) -> const u16* {
    return (t < nPre) ? cvb + hoff + (size_t)t * 64 * D_
                      : vts + hoff + (size_t)(t - nPre) * 64 * D_;
  };
  auto stageK = [&](int buf, int t) {
    const u16* base = kbase(t);
    for (int r = 0; r < 2; ++r) {
      int ci = wid * 2 + r;
      int row = ci * 8 + (lane >> 3);
      int gb = ((lane & 7) * 16) ^ ((row & 7) << 4);
      gld_lds16((const char*)base + (size_t)row * 128 + gb, &lK[buf][ci * 512]);
    }
  };
  auto loadV = [&](int t) {              // issue-early: global -> regs
    const u16* base = vbase(t) + (size_t)(tid >> 2) * D_ + (tid & 3) * 16;
    vr0 = *(const uint4*)base;
    vr1 = *(const uint4*)(base + 8);
  };
  auto writeV = [&](int buf) {           // write-late: regs -> LDS transposed
    int key = tid >> 2, d0 = (tid & 3) * 16;
    const u16* s0 = (const u16*)&vr0;
    const u16* s1 = (const u16*)&vr1;
#pragma unroll
    for (int j = 0; j < 16; ++j) {
      u16 val = (j < 8) ? s0[j] : s1[j - 8];
      int d = d0 + j;
      *(u16*)((char*)&lV[buf][0] + (((d * 128) + key * 2) ^ ((d & 7) << 4))) = val;
    }
  };

  stageK(0, 0);
  loadV(0);
  int cur = 0;
  for (int t = 0; t < ntl; ++t) {
    writeV(cur);
    __syncthreads();   // K(cur) staged (vmcnt drained), V(cur) visible
    if (t + 1 < ntl) { stageK(cur ^ 1, t + 1); loadV(t + 1); }

    // S = Q K^T  (16q x 64keys per wave)
    const char* pk = (const char*)&lK[cur][0];
    f32x4 s[4];
#pragma unroll
    for (int kb = 0; kb < 4; ++kb) {
      int krow = kb * 16 + c;
      int sw = (krow & 7) << 4;
      bf16x8 k0 = *(const bf16x8*)(pk + krow * 128 + ((g * 16) ^ sw));
      bf16x8 k1 = *(const bf16x8*)(pk + krow * 128 + ((64 + g * 16) ^ sw));
      f32x4 z = {};
      z = __builtin_amdgcn_mfma_f32_16x16x32_bf16(q0, k0, z, 0, 0, 0);
      z = __builtin_amdgcn_mfma_f32_16x16x32_bf16(q1, k1, z, 0, 0, 0);
      s[kb] = z;
    }

    if (t == ntl - 1) {  // causal mask on the diagonal self tile
#pragma unroll
      for (int kb = 0; kb < 4; ++kb) {
        int key = kb * 16 + c;
#pragma unroll
        for (int r = 0; r < 4; ++r)
          if (key > wid * 16 + g * 4 + r) s[kb][r] = -3.0e38f;
      }
    }

    // online softmax (rows = 4g+r, cols across kb and the 16 lanes of group)
    float alpha[4];
#pragma unroll
    for (int r = 0; r < 4; ++r) {
      float mx = fmaxf(fmaxf(s[0][r], s[1][r]), fmaxf(s[2][r], s[3][r]));
      mx = fmaxf(mx, __shfl_xor(mx, 1));
      mx = fmaxf(mx, __shfl_xor(mx, 2));
      mx = fmaxf(mx, __shfl_xor(mx, 4));
      mx = fmaxf(mx, __shfl_xor(mx, 8));
      float mn = fmaxf(m_[r], mx);
      alpha[r] = exp2f(m_[r] - mn);
      m_[r] = mn;
    }

    u16* pp = &lP[wid][0];
    float rsum[4] = {0.f, 0.f, 0.f, 0.f};
#pragma unroll
    for (int kb = 0; kb < 4; ++kb) {
#pragma unroll
      for (int r = 0; r < 4; ++r) {
        float p = exp2f(s[kb][r] - m_[r]);
        rsum[r] += p;
        int row = g * 4 + r;
        *(u16*)((char*)pp + (((row * 128) + (kb * 16 + c) * 2) ^ ((row & 7) << 4))) = f2bf(p);
      }
    }
#pragma unroll
    for (int r = 0; r < 4; ++r) {
      float v = rsum[r];
      v += __shfl_xor(v, 1);
      v += __shfl_xor(v, 2);
      v += __shfl_xor(v, 4);
      v += __shfl_xor(v, 8);
      l_[r] = l_[r] * alpha[r] + v;
    }
#pragma unroll
    for (int db = 0; db < 4; ++db)
#pragma unroll
      for (int r = 0; r < 4; ++r) acc[db][r] *= alpha[r];

    // PV: A = P (row=q, k=key), B = V[key][d] from transposed lV
    int swp = (c & 7) << 4;
    bf16x8 pa0 = *(const bf16x8*)((const char*)pp + c * 128 + ((g * 16) ^ swp));
    bf16x8 pa1 = *(const bf16x8*)((const char*)pp + c * 128 + ((64 + g * 16) ^ swp));
    const char* pv = (const char*)&lV[cur][0];
#pragma unroll
    for (int db = 0; db < 4; ++db) {
      int d = db * 16 + c;
      int swv = (d & 7) << 4;
      bf16x8 v0 = *(const bf16x8*)(pv + d * 128 + ((g * 16) ^ swv));
      bf16x8 v1 = *(const bf16x8*)(pv + d * 128 + ((64 + g * 16) ^ swv));
      acc[db] = __builtin_amdgcn_mfma_f32_16x16x32_bf16(pa0, v0, acc[db], 0, 0, 0);
      acc[db] = __builtin_amdgcn_mfma_f32_16x16x32_bf16(pa1, v1, acc[db], 0, 0, 0);
    }
    cur ^= 1;
  }

  // normalize + store y as bf16 rows [b*T+t][h*64+d]
  const int b = bh >> 4, h = bh & 15;
#pragma unroll
  for (int r = 0; r < 4; ++r) {
    float inv = 1.0f / l_[r];
    int trow = qbase + wid * 16 + g * 4 + r;
    size_t rowoff = ((size_t)(b * T_ + trow)) * C_ + h * D_;
#pragma unroll
    for (int db = 0; db < 4; ++db)
      y[rowoff + db * 16 + c] = f2bf(acc[db][r] * inv);
  }
}

extern "C" void kernel_launch(void* const* d_in, const int* in_sizes, int n_in,
                              void* d_out, int out_size, void* d_ws, size_t ws_size,
                              hipStream_t stream) {
  const float* x  = (const float*)d_in[0];
  const float* Wa = (const float*)d_in[1];
  const float* Wp = (const float*)d_in[2];
  const float* ck = (const float*)d_in[3];
  const float* cv = (const float*)d_in[4];
  float* out = (float*)d_out;
  char* ws = (char*)d_ws;

  u16* xb  = (u16*)(ws + (size_t)0);
  u16* waT = (u16*)(ws + (size_t)8  * 1024 * 1024);  // 6 MB
  u16* wpT = (u16*)(ws + (size_t)14 * 1024 * 1024);  // 2 MB
  u16* qtb = (u16*)(ws + (size_t)16 * 1024 * 1024);  // 8 MB
  u16* ktb = (u16*)(ws + (size_t)24 * 1024 * 1024);  // 8 MB
  u16* vtb = (u16*)(ws + (size_t)32 * 1024 * 1024);  // 8 MB
  u16* ckb = (u16*)(ws + (size_t)40 * 1024 * 1024);  // 8 MB
  u16* cvb = (u16*)(ws + (size_t)48 * 1024 * 1024);  // 8 MB
  u16* yb  = (u16*)(ws + (size_t)56 * 1024 * 1024);  // 8 MB (total 64 MB)

  k_cast<<<4096, 256, 0, stream>>>(x, xb, M_ * C_);
  k_tcast<<<dim3(N1_ / 32, C_ / 32), dim3(32, 8), 0, stream>>>(Wa, waT, C_, N1_);
  k_tcast<<<dim3(C_ / 32, C_ / 32), dim3(32, 8), 0, stream>>>(Wp, wpT, C_, C_);
  k_cast<<<4096, 256, 0, stream>>>(ck, ckb, B_ * H_ * P_ * D_);
  k_cast<<<4096, 256, 0, stream>>>(cv, cvb, B_ * H_ * P_ * D_);

  // qkv = x @ W_attn, scattered into q/k/v (B,H,T,D), q pre-scaled
  k_gemm<0><<<dim3(N1_ / 128, M_ / 128), 256, 0, stream>>>(xb, waT, qtb, ktb, vtb, N1_, C_);
  // flash attention over [cache | causal self]
  k_attn<<<dim3(T_ / 64, B_ * H_), 256, 0, stream>>>(qtb, ktb, vtb, ckb, cvb, yb);
  // out = y @ W_proj (fp32 out)
  k_gemm<1><<<dim3(C_ / 128, M_ / 128), 256, 0, stream>>>(yb, wpT, out, nullptr, nullptr, C_, C_);
}

// Round 4
// 339.639 us; speedup vs baseline: 1.3463x; 1.3463x over previous
//
#include <hip/hip_runtime.h>
#include <stdint.h>

typedef unsigned short u16;
typedef unsigned int u32;
typedef short bf16x8 __attribute__((ext_vector_type(8)));
typedef float f32x4 __attribute__((ext_vector_type(4)));
typedef u32 u32x4 __attribute__((ext_vector_type(4)));

#define DEVI static __device__ __forceinline__

// ---- fixed problem shapes ----
#define B_ 2
#define T_ 2048
#define C_ 1024
#define H_ 16
#define D_ 64
#define P_ 2048
#define M_ (B_ * T_)   // 4096
#define N1_ (3 * C_)   // 3072
#define LOG2E 1.44269504088896340736f

DEVI u16 f2bf(float f) {
  union { float f; u32 u; } v; v.f = f;
  u32 r = v.u + 0x7fffu + ((v.u >> 16) & 1u);  // RNE
  return (u16)(r >> 16);
}

DEVI u32 cvtpk(float lo, float hi) {   // bf16(lo) | bf16(hi)<<16
  u32 r;
  asm("v_cvt_pk_bf16_f32 %0, %1, %2" : "=v"(r) : "v"(lo), "v"(hi));
  return r;
}

DEVI void gld_lds16(const void* g, void* l) {
  __builtin_amdgcn_global_load_lds((__attribute__((address_space(1))) void*)g,
                                   (__attribute__((address_space(3))) void*)l,
                                   16, 0, 0);
}

DEVI f32x4 mfma16(bf16x8 a, bf16x8 b, f32x4 c) {
  return __builtin_amdgcn_mfma_f32_16x16x32_bf16(a, b, c, 0, 0, 0);
}

// ---------- cast f32 -> bf16 (vectorized) ----------
__global__ void k_cast(const float* __restrict__ src, u16* __restrict__ dst, int n) {
  int i = (blockIdx.x * 256 + threadIdx.x) * 4;
  if (i >= n) return;
  float4 v = *(const float4*)(src + i);
  ushort4 o;
  o.x = f2bf(v.x); o.y = f2bf(v.y); o.z = f2bf(v.z); o.w = f2bf(v.w);
  *(ushort4*)(dst + i) = o;
}

// ---------- transpose+cast: src[R][C] f32 -> dst[C][R] bf16 ----------
__global__ void k_tcast(const float* __restrict__ src, u16* __restrict__ dst,
                        int R, int C) {
  __shared__ float t[32][33];
  int c0 = blockIdx.x * 32, r0 = blockIdx.y * 32;
  int tx = threadIdx.x, ty = threadIdx.y;
  for (int i = ty; i < 32; i += 8)
    t[i][tx] = src[(size_t)(r0 + i) * C + c0 + tx];
  __syncthreads();
  for (int i = ty; i < 32; i += 8)
    dst[(size_t)(c0 + i) * R + r0 + tx] = f2bf(t[tx][i]);
}

// ---------- per-head transpose+cast: cache_v (bh,P,D) f32 -> (bh,D,P) bf16 ----------
__global__ void k_tcastv(const float* __restrict__ src, u16* __restrict__ dst) {
  __shared__ float t[32][33];
  int bh = blockIdx.z;
  int p0 = blockIdx.x * 32, d0 = blockIdx.y * 32;
  int tx = threadIdx.x, ty = threadIdx.y;
  const float* s = src + ((size_t)bh * P_ + p0) * D_ + d0;
  for (int i = ty; i < 32; i += 8)
    t[i][tx] = s[(size_t)i * D_ + tx];
  __syncthreads();
  u16* d = dst + ((size_t)bh * D_ + d0) * P_ + p0;
  for (int i = ty; i < 32; i += 8)
    d[(size_t)i * P_ + tx] = f2bf(t[tx][i]);
}

// ---------- GEMM: A[M][K] bf16 (row-major), Bt[N][K] bf16 -> out ----------
// MODE 0: qkv epilogue: q,k -> (B,H,T,D) (q scaled by 1/8*log2e), v -> (B,H,D,T)
// MODE 1: plain fp32 row-major output [M][N]
template <int MODE>
__launch_bounds__(256)
__global__ void k_gemm(const u16* __restrict__ A, const u16* __restrict__ Bt,
                       void* __restrict__ out0, void* __restrict__ out1,
                       void* __restrict__ out2, int N, int K) {
  __shared__ __align__(16) u16 lA[2][128 * 32];
  __shared__ __align__(16) u16 lB[2][128 * 32];
  const int tid = threadIdx.x, lane = tid & 63, wid = tid >> 6;
  const int wr = wid >> 1, wc = wid & 1;
  const int c = lane & 15, g = lane >> 4;
  const int nt = blockIdx.x, mt = blockIdx.y;
  const int nk = K >> 5;

  f32x4 acc[4][4] = {};

  auto stage = [&](int buf, int kt) {
    for (int r = 0; r < 2; ++r) {
      int ci = wid * 2 + r;
      int row = ci * 16 + (lane >> 2);
      int gb = ((lane & 3) * 16) ^ ((row & 3) << 4);
      gld_lds16((const char*)A + ((size_t)(mt * 128 + row) * K + kt * 32) * 2 + gb,
                &lA[buf][ci * 512]);
      gld_lds16((const char*)Bt + ((size_t)(nt * 128 + row) * K + kt * 32) * 2 + gb,
                &lB[buf][ci * 512]);
    }
  };

  stage(0, 0);
  int cur = 0;
  for (int kt = 0; kt < nk; ++kt) {
    __syncthreads();            // drains vmcnt: buf[cur] ready
    if (kt + 1 < nk) stage(cur ^ 1, kt + 1);
    const char* pa = (const char*)&lA[cur][0];
    const char* pb = (const char*)&lB[cur][0];
    bf16x8 af[4], bfr[4];
#pragma unroll
    for (int i = 0; i < 4; ++i) {
      int ar = wr * 64 + i * 16 + c;
      af[i] = *(const bf16x8*)(pa + ar * 64 + ((g * 16) ^ ((ar & 3) << 4)));
      int br = wc * 64 + i * 16 + c;
      bfr[i] = *(const bf16x8*)(pb + br * 64 + ((g * 16) ^ ((br & 3) << 4)));
    }
#pragma unroll
    for (int i = 0; i < 4; ++i)
#pragma unroll
      for (int j = 0; j < 4; ++j)
        acc[i][j] = mfma16(af[i], bfr[j], acc[i][j]);
    cur ^= 1;
  }

  if (MODE == 0) {
    const float qs = 0.125f * LOG2E;  // 1/sqrt(D) * log2(e) folded into q
#pragma unroll
    for (int i = 0; i < 4; ++i) {
      int rbase = mt * 128 + wr * 64 + i * 16 + g * 4;
#pragma unroll
      for (int j = 0; j < 4; ++j) {
        int col = nt * 128 + wc * 64 + j * 16 + c;
        int which = col >> 10, cc = col & 1023;
        int h = cc >> 6, d = cc & 63;
        if (which == 2) {
          // v -> svT[(b*16+h)*64 + d][t], 4 consecutive t per lane
          ushort4 o;
          o.x = f2bf(acc[i][j][0]); o.y = f2bf(acc[i][j][1]);
          o.z = f2bf(acc[i][j][2]); o.w = f2bf(acc[i][j][3]);
          int b = rbase >> 11, t0 = rbase & 2047;
          *(ushort4*)&((u16*)out2)[((size_t)((b * H_ + h) * D_) + d) * T_ + t0] = o;
        } else {
          u16* dst = which == 0 ? (u16*)out0 : (u16*)out1;
          float sc = which == 0 ? qs : 1.0f;
#pragma unroll
          for (int r = 0; r < 4; ++r) {
            int m = rbase + r;
            int b = m >> 11, t = m & 2047;
            dst[((size_t)(b * H_ + h) * T_ + t) * D_ + d] = f2bf(acc[i][j][r] * sc);
          }
        }
      }
    }
  } else {
    float* O = (float*)out0;
#pragma unroll
    for (int i = 0; i < 4; ++i) {
      int rbase = mt * 128 + wr * 64 + i * 16 + g * 4;
#pragma unroll
      for (int j = 0; j < 4; ++j) {
        int col = nt * 128 + wc * 64 + j * 16 + c;
#pragma unroll
        for (int r = 0; r < 4; ++r)
          O[(size_t)(rbase + r) * N + col] = acc[i][j][r];
      }
    }
  }
}

// ---------- flash attention over [prefix P=2048][causal self T] ----------
// grid: (T/64 qtiles, B*H). 128 thr = 2 waves, 32 q-rows per wave (2 q-blocks).
// Swapped QK^T (mfma(K,Q)) -> per-lane softmax (q = c). K rows are slot-permuted
// per mfma n: key(n,s) = 2n + 32*((s>>1)&1) + 8*(s>>2) + (s&1), chosen so S^T
// lands directly in PV's B-fragment layout (P repack = 8 cvt_pk, no lane perms).
// V is pre-transposed in global ([d][key]) and staged like K.
// Row swizzle h(R) = (R ^ (R>>3)) & 7 spreads both K- and V-read patterns.
__launch_bounds__(128, 2)
__global__ void k_attn(const u16* __restrict__ qt, const u16* __restrict__ kts,
                       const u16* __restrict__ svT, const u16* __restrict__ ckb,
                       const u16* __restrict__ cvT, u16* __restrict__ y) {
  __shared__ __align__(16) u16 lK[2][64 * 64];   // [key][d]  (8 KB each buf)
  __shared__ __align__(16) u16 lV[2][64 * 64];   // [d][key]
  const int tid = threadIdx.x, lane = tid & 63, wid = tid >> 6;
  const int c = lane & 15, g = lane >> 4;
  const int qtile = blockIdx.x, bh = blockIdx.y;
  const int qbase = qtile * 64;
  const size_t hoff = (size_t)bh * (P_ * D_);   // same elem count for all per-head bufs

  // Q fragments (B-operand) for the wave's 2 q-blocks
  bf16x8 qf[2][2];
#pragma unroll
  for (int qb = 0; qb < 2; ++qb) {
    const u16* qp = qt + hoff + (size_t)(qbase + wid * 32 + qb * 16 + c) * D_;
    qf[qb][0] = *(const bf16x8*)(qp + g * 8);
    qf[qb][1] = *(const bf16x8*)(qp + 32 + g * 8);
  }

  // precomputed LDS read byte offsets (loop-invariant)
  int ofsK[4][2], ofsV[4][2];
  {
    int r0 = ((c >> 1) & 1) * 32 + (c >> 2) * 8 + (c & 1);
#pragma unroll
    for (int n = 0; n < 4; ++n) {
      int R = 2 * n + r0;
      int h = (R ^ (R >> 3)) & 7;
      ofsK[n][0] = R * 128 + ((g * 16) ^ (h * 16));
      ofsK[n][1] = R * 128 + ((64 + g * 16) ^ (h * 16));
    }
#pragma unroll
    for (int db = 0; db < 4; ++db) {
      int R = db * 16 + c;
      int h = (R ^ (R >> 3)) & 7;
      ofsV[db][0] = R * 128 + ((g * 16) ^ (h * 16));
      ofsV[db][1] = R * 128 + ((64 + g * 16) ^ (h * 16));
    }
  }

  float m_[2] = {-3.0e38f, -3.0e38f}, l_[2] = {0.f, 0.f};
  f32x4 acc[2][4] = {};

  const int nPre = P_ / 64;            // 32 prefix tiles
  const int ntl = nPre + qtile + 1;    // + self tiles, last one masked

  auto stage = [&](int buf, int t) {
    const u16* kb = (t < nPre) ? ckb + hoff + (size_t)t * 64 * D_
                               : kts + hoff + (size_t)(t - nPre) * 64 * D_;
#pragma unroll
    for (int q = 0; q < 4; ++q) {
      int chunk = q * 128 + wid * 64 + lane;
      int R = chunk >> 3, s = chunk & 7;
      int h = (R ^ (R >> 3)) & 7;
      gld_lds16((const char*)kb + R * 128 + ((s * 16) ^ (h * 16)),
                (char*)&lK[buf][0] + (q * 128 + wid * 64) * 16);
    }
    const u16* vb = (t < nPre) ? cvT + hoff : svT + hoff;
    int key0 = ((t < nPre) ? t : (t - nPre)) * 64;
#pragma unroll
    for (int q = 0; q < 4; ++q) {
      int chunk = q * 128 + wid * 64 + lane;
      int R = chunk >> 3, s = chunk & 7;
      int h = (R ^ (R >> 3)) & 7;
      gld_lds16((const char*)(vb + (size_t)R * T_ + key0) + ((s * 16) ^ (h * 16)),
                (char*)&lV[buf][0] + (q * 128 + wid * 64) * 16);
    }
  };

  stage(0, 0);
  int cur = 0;
  for (int t = 0; t < ntl; ++t) {
    __syncthreads();   // buf[cur] staged (vmcnt drained by barrier)
    if (t + 1 < ntl) stage(cur ^ 1, t + 1);

    const char* pk = (const char*)&lK[cur][0];
    const char* pv = (const char*)&lV[cur][0];
    bf16x8 kf[4][2], vf[4][2];
#pragma unroll
    for (int n = 0; n < 4; ++n) {
      kf[n][0] = *(const bf16x8*)(pk + ofsK[n][0]);
      kf[n][1] = *(const bf16x8*)(pk + ofsK[n][1]);
    }
#pragma unroll
    for (int db = 0; db < 4; ++db) {
      vf[db][0] = *(const bf16x8*)(pv + ofsV[db][0]);
      vf[db][1] = *(const bf16x8*)(pv + ofsV[db][1]);
    }
    const bool lastT = (t == ntl - 1);

#pragma unroll
    for (int qb = 0; qb < 2; ++qb) {
      // S^T = K Q^T : lane holds s4[n][r] = S[q=c][key = 2n + 32*(r>>1) + 8g + (r&1)]
      f32x4 s4[4];
#pragma unroll
      for (int n = 0; n < 4; ++n) {
        f32x4 z = {};
        z = mfma16(kf[n][0], qf[qb][0], z);
        z = mfma16(kf[n][1], qf[qb][1], z);
        s4[n] = z;
      }
      if (lastT) {
        int qloc = wid * 32 + qb * 16 + c;
#pragma unroll
        for (int n = 0; n < 4; ++n)
#pragma unroll
          for (int r = 0; r < 4; ++r) {
            int key = 2 * n + (r >> 1) * 32 + 8 * g + (r & 1);
            if (key > qloc) s4[n][r] = -3.0e38f;
          }
      }
      // per-lane online softmax (all 16 vals are row q=c; reduce over g via shfl)
      float mx = fmaxf(fmaxf(fmaxf(s4[0][0], s4[0][1]), fmaxf(s4[0][2], s4[0][3])),
                       fmaxf(fmaxf(s4[1][0], s4[1][1]), fmaxf(s4[1][2], s4[1][3])));
      mx = fmaxf(mx, fmaxf(fmaxf(fmaxf(s4[2][0], s4[2][1]), fmaxf(s4[2][2], s4[2][3])),
                           fmaxf(fmaxf(s4[3][0], s4[3][1]), fmaxf(s4[3][2], s4[3][3]))));
      mx = fmaxf(mx, __shfl_xor(mx, 16));
      mx = fmaxf(mx, __shfl_xor(mx, 32));
      float mn = fmaxf(m_[qb], mx);
      float alpha = exp2f(m_[qb] - mn);
      m_[qb] = mn;
      float p[4][4];
      float sum = 0.f;
#pragma unroll
      for (int n = 0; n < 4; ++n)
#pragma unroll
        for (int r = 0; r < 4; ++r) {
          p[n][r] = exp2f(s4[n][r] - mn);
          sum += p[n][r];
        }
      sum += __shfl_xor(sum, 16);
      sum += __shfl_xor(sum, 32);
      l_[qb] = l_[qb] * alpha + sum;
#pragma unroll
      for (int db = 0; db < 4; ++db) acc[qb][db] *= alpha;
      // pack P directly into PV B-fragments (keys 0..31 / 32..63), no lane perms
      union { u32x4 w; bf16x8 v; } pa0, pa1;
#pragma unroll
      for (int jw = 0; jw < 4; ++jw) {
        pa0.w[jw] = cvtpk(p[jw][0], p[jw][1]);
        pa1.w[jw] = cvtpk(p[jw][2], p[jw][3]);
      }
#pragma unroll
      for (int db = 0; db < 4; ++db) {
        acc[qb][db] = mfma16(vf[db][0], pa0.v, acc[qb][db]);
        acc[qb][db] = mfma16(vf[db][1], pa1.v, acc[qb][db]);
      }
    }
    cur ^= 1;
  }

  // epilogue: O^T in acc — lane (c,g): O[q = base + c][d = db*16 + 4g + r]
  const int b = bh >> 4, h = bh & 15;
#pragma unroll
  for (int qb = 0; qb < 2; ++qb) {
    float inv = 1.0f / l_[qb];
    int trow = qbase + wid * 32 + qb * 16 + c;
    size_t rowoff = ((size_t)(b * T_ + trow)) * C_ + h * D_;
#pragma unroll
    for (int db = 0; db < 4; ++db) {
      ushort4 o;
      o.x = f2bf(acc[qb][db][0] * inv);
      o.y = f2bf(acc[qb][db][1] * inv);
      o.z = f2bf(acc[qb][db][2] * inv);
      o.w = f2bf(acc[qb][db][3] * inv);
      *(ushort4*)&y[rowoff + db * 16 + 4 * g] = o;
    }
  }
}

extern "C" void kernel_launch(void* const* d_in, const int* in_sizes, int n_in,
                              void* d_out, int out_size, void* d_ws, size_t ws_size,
                              hipStream_t stream) {
  const float* x  = (const float*)d_in[0];
  const float* Wa = (const float*)d_in[1];
  const float* Wp = (const float*)d_in[2];
  const float* ck = (const float*)d_in[3];
  const float* cv = (const float*)d_in[4];
  float* out = (float*)d_out;
  char* ws = (char*)d_ws;

  u16* xb  = (u16*)(ws + (size_t)0);
  u16* waT = (u16*)(ws + (size_t)8  * 1024 * 1024);  // 6 MB
  u16* wpT = (u16*)(ws + (size_t)14 * 1024 * 1024);  // 2 MB
  u16* qtb = (u16*)(ws + (size_t)16 * 1024 * 1024);  // 8 MB (B,H,T,D)
  u16* ktb = (u16*)(ws + (size_t)24 * 1024 * 1024);  // 8 MB (B,H,T,D)
  u16* svT = (u16*)(ws + (size_t)32 * 1024 * 1024);  // 8 MB (B,H,D,T)
  u16* ckb = (u16*)(ws + (size_t)40 * 1024 * 1024);  // 8 MB (B,H,P,D)
  u16* cvT = (u16*)(ws + (size_t)48 * 1024 * 1024);  // 8 MB (B,H,D,P)
  u16* yb  = (u16*)(ws + (size_t)56 * 1024 * 1024);  // 8 MB

  k_cast<<<4096, 256, 0, stream>>>(x, xb, M_ * C_);
  k_tcast<<<dim3(N1_ / 32, C_ / 32), dim3(32, 8), 0, stream>>>(Wa, waT, C_, N1_);
  k_tcast<<<dim3(C_ / 32, C_ / 32), dim3(32, 8), 0, stream>>>(Wp, wpT, C_, C_);
  k_cast<<<4096, 256, 0, stream>>>(ck, ckb, B_ * H_ * P_ * D_);
  k_tcastv<<<dim3(P_ / 32, D_ / 32, B_ * H_), dim3(32, 8), 0, stream>>>(cv, cvT);

  // qkv = x @ W_attn, scattered into q/k (B,H,T,D) and v^T (B,H,D,T)
  k_gemm<0><<<dim3(N1_ / 128, M_ / 128), 256, 0, stream>>>(xb, waT, qtb, ktb, svT, N1_, C_);
  // flash attention over [cache | causal self]
  k_attn<<<dim3(T_ / 64, B_ * H_), 128, 0, stream>>>(qtb, ktb, svT, ckb, cvT, yb);
  // out = y @ W_proj (fp32 out)
  k_gemm<1><<<dim3(C_ / 128, M_ / 128), 256, 0, stream>>>(yb, wpT, out, nullptr, nullptr, C_, C_);
}